// Round 2
// baseline (185.463 us; speedup 1.0000x reference)
//
#include <hip/hip_runtime.h>
#include <cstdint>
#include <cstddef>

typedef _Float16 half8  __attribute__((ext_vector_type(8)));
typedef _Float16 half4v __attribute__((ext_vector_type(4)));
typedef float    f32x4  __attribute__((ext_vector_type(4)));

__device__ __forceinline__ f32x4 fzero4() {
  f32x4 v; v[0] = v[1] = v[2] = v[3] = 0.0f; return v;
}

// async global->LDS, 16B per lane. LDS dest must be wave-uniform base (+lane*16 implicit).
__device__ __forceinline__ void gload16(const void* g, void* l) {
  __builtin_amdgcn_global_load_lds(
      (const __attribute__((address_space(1))) unsigned int*)g,
      (__attribute__((address_space(3))) unsigned int*)l, 16, 0, 0);
}

#define MFMA(a, b, c) __builtin_amdgcn_mfma_f32_16x16x32_f16(a, b, c, 0, 0, 0)

// ---------------------------------------------------------------- conversion
struct CvtArgs {
  const float* src[7];
  _Float16*    dst[7];
  int          n[7];
};

__global__ __launch_bounds__(256) void cvt_kernel(CvtArgs a) {
  const int z = blockIdx.y;
  const float4* __restrict__ s = (const float4*)a.src[z];
  half4v* __restrict__ d = (half4v*)a.dst[z];
  const int n4 = a.n[z] >> 2;
  for (int i = blockIdx.x * blockDim.x + threadIdx.x; i < n4;
       i += gridDim.x * blockDim.x) {
    float4 v = s[i];
    half4v h;
    h[0] = (_Float16)v.x; h[1] = (_Float16)v.y;
    h[2] = (_Float16)v.z; h[3] = (_Float16)v.w;
    d[i] = h;
  }
}

// ------------------------------------------------------- mask normalization
// Reference mask dtype is bool; harness may push it as int32 ("integer ->
// const int*") or as raw bytes. Detect on-device: for int32-encoded 0/1,
// bytes at offset 4k+1 are ALWAYS zero; for bool-bytes they are random 0/1.
// Sampling 1024 such positions misdetects with prob 2^-1024. Deterministic
// for fixed inputs -> graph-safe. Output: 1 byte per element.
__global__ __launch_bounds__(256) void maskcvt_kernel(
    const unsigned char* __restrict__ src, unsigned char* __restrict__ dst,
    int n) {
  const int lane = threadIdx.x & 63;
  unsigned probe = 0;
#pragma unroll
  for (int e = 0; e < 16; ++e) probe |= src[4 * (lane * 16 + e) + 1];
  const bool isbool = __any(probe != 0);

  const int n4 = n >> 2;
  uchar4* __restrict__ d4 = (uchar4*)dst;
  if (isbool) {
    const uchar4* __restrict__ s4 = (const uchar4*)src;
    for (int i = blockIdx.x * blockDim.x + threadIdx.x; i < n4;
         i += gridDim.x * blockDim.x)
      d4[i] = s4[i];
  } else {
    const int4* __restrict__ s4 = (const int4*)src;
    for (int i = blockIdx.x * blockDim.x + threadIdx.x; i < n4;
         i += gridDim.x * blockDim.x) {
      int4 w = s4[i];
      uchar4 r;
      r.x = (unsigned char)(w.x != 0);
      r.y = (unsigned char)(w.y != 0);
      r.z = (unsigned char)(w.z != 0);
      r.w = (unsigned char)(w.w != 0);
      d4[i] = r;
    }
  }
}

// ---------------------------------------------------------------- projections
// C = A(4096x1024) @ W^T(1024x1024) + bias; z=0: Q (+LN, ->[B,H,T,64]),
// z=1: K (+LN, ->[B,H,T,64]), z=2: V (-> transposed [B,H,64,T]).
__global__ __launch_bounds__(256) void proj_kernel(
    const _Float16* __restrict__ q16, const _Float16* __restrict__ k16,
    const _Float16* __restrict__ v16, const _Float16* __restrict__ w16,
    const float* __restrict__ bq, const float* __restrict__ bk,
    const float* __restrict__ bv,
    const float* __restrict__ qg, const float* __restrict__ qbt,
    const float* __restrict__ kg, const float* __restrict__ kbt,
    _Float16* __restrict__ Qln, _Float16* __restrict__ Kln,
    _Float16* __restrict__ VT) {
  __shared__ _Float16 As[128 * 64];
  __shared__ _Float16 Bs[128 * 64];

  const int tid = threadIdx.x;
  const int w = tid >> 6, lane = tid & 63, g = lane >> 4, l15 = lane & 15;
  const int bn = blockIdx.x;  // 0..7   (N tiles)
  const int bm = blockIdx.y;  // 0..31  (M tiles)
  const int z = blockIdx.z;   // 0..2

  const _Float16* A = (z == 0) ? q16 : ((z == 1) ? k16 : v16);
  const _Float16* W = w16 + (size_t)z * (1024 * 1024);
  const float* bias = (z == 0) ? bq : ((z == 1) ? bk : bv);

  const int wr = w >> 1, wc = w & 1;
  const int srow = (w << 3) + (lane >> 3);  // + r*32
  const int scol = (lane & 7) << 3;         // element col within BK

  f32x4 acc[4][4];
#pragma unroll
  for (int i = 0; i < 4; ++i)
#pragma unroll
    for (int j = 0; j < 4; ++j) acc[i][j] = fzero4();

  for (int kt = 0; kt < 16; ++kt) {
    __syncthreads();
#pragma unroll
    for (int r = 0; r < 4; ++r) {
      const int row = r * 32 + srow;
      gload16(A + (size_t)(bm * 128 + row) * 1024 + kt * 64 + scol,
              &As[(r * 32 + (w << 3)) * 64]);
      gload16(W + (size_t)(bn * 128 + row) * 1024 + kt * 64 + scol,
              &Bs[(r * 32 + (w << 3)) * 64]);
    }
    asm volatile("s_waitcnt vmcnt(0)" ::: "memory");
    __syncthreads();

#pragma unroll
    for (int kk = 0; kk < 2; ++kk) {
      half8 a[4], b[4];
#pragma unroll
      for (int mi = 0; mi < 4; ++mi)
        a[mi] = *(const half8*)&As[(wr * 64 + mi * 16 + l15) * 64 + kk * 32 + g * 8];
#pragma unroll
      for (int nj = 0; nj < 4; ++nj)
        b[nj] = *(const half8*)&Bs[(wc * 64 + nj * 16 + l15) * 64 + kk * 32 + g * 8];
#pragma unroll
      for (int mi = 0; mi < 4; ++mi)
#pragma unroll
        for (int nj = 0; nj < 4; ++nj)
          acc[mi][nj] = MFMA(a[mi], b[nj], acc[mi][nj]);
    }
  }

  const int colbase = bn * 128 + wc * 64;  // + nj*16 + l15
  const int h = colbase >> 6;              // head
  const int rowbase = bm * 128 + wr * 64;  // + mi*16 + g*4 + j

  float biasv[4];
#pragma unroll
  for (int nj = 0; nj < 4; ++nj) biasv[nj] = bias[colbase + nj * 16 + l15];

  if (z < 2) {
    const float* gamma = (z == 0) ? qg : kg;
    const float* beta = (z == 0) ? qbt : kbt;
    _Float16* dst = (z == 0) ? Qln : Kln;
    float gam[4], bet[4];
#pragma unroll
    for (int nj = 0; nj < 4; ++nj) {
      gam[nj] = gamma[nj * 16 + l15];
      bet[nj] = beta[nj * 16 + l15];
    }
#pragma unroll
    for (int mi = 0; mi < 4; ++mi) {
#pragma unroll
      for (int j = 0; j < 4; ++j) {
        float vals[4], s = 0.f, s2 = 0.f;
#pragma unroll
        for (int nj = 0; nj < 4; ++nj) {
          float v = acc[mi][nj][j] + biasv[nj];
          vals[nj] = v; s += v; s2 += v * v;
        }
#pragma unroll
        for (int m = 1; m < 16; m <<= 1) {
          s += __shfl_xor(s, m, 64);
          s2 += __shfl_xor(s2, m, 64);
        }
        const float mu = s * (1.0f / 64.0f);
        const float var = s2 * (1.0f / 64.0f) - mu * mu;
        const float rs = rsqrtf(var + 1e-5f);
        const int r = rowbase + mi * 16 + g * 4 + j;
        const int b = r >> 10, t = r & 1023;
        _Float16* drow = dst + ((size_t)((b * 16 + h) * 1024 + t)) * 64;
#pragma unroll
        for (int nj = 0; nj < 4; ++nj)
          drow[nj * 16 + l15] =
              (_Float16)((vals[nj] - mu) * rs * gam[nj] + bet[nj]);
      }
    }
  } else {
    // V: write transposed [B][H][64][1024], pack 4 consecutive t as 8B
#pragma unroll
    for (int mi = 0; mi < 4; ++mi) {
      const int r0 = rowbase + mi * 16 + g * 4;
      const int b = r0 >> 10, t0 = r0 & 1023;
#pragma unroll
      for (int nj = 0; nj < 4; ++nj) {
        const int dk = nj * 16 + l15;
        half4v pk;
#pragma unroll
        for (int j = 0; j < 4; ++j)
          pk[j] = (_Float16)(acc[mi][nj][j] + biasv[nj]);
        *(half4v*)&VT[((size_t)((b * 16 + h) * 64 + dk)) * 1024 + t0] = pk;
      }
    }
  }
}

// ---------------------------------------------------------------- attention
// grid (8 qtiles, 64 b*h); 4 waves x 32 q-rows; flash online softmax over 16
// K-tiles of 64. Q,K: [B,H,T,64]; V: [B,H,64,T]; mask: [B,T,T] bytes (1=masked).
__global__ __launch_bounds__(256) void attn_kernel(
    const _Float16* __restrict__ Qln, const _Float16* __restrict__ Kln,
    const _Float16* __restrict__ VT, const unsigned char* __restrict__ mask,
    _Float16* __restrict__ X) {
  __shared__ _Float16 Qs[128 * 64];
  __shared__ _Float16 Ks[64 * 64];
  __shared__ _Float16 Vs[64 * 64];
  __shared__ _Float16 Ps[128 * 72];  // padded: 144B rows, 16B aligned
  __shared__ unsigned char Ms[128 * 64];

  const int tid = threadIdx.x;
  const int w = tid >> 6, lane = tid & 63, g = lane >> 4, l15 = lane & 15;
  const int qt = blockIdx.x;  // 0..7
  const int bh = blockIdx.y;  // 0..63
  const int b = bh >> 4, h = bh & 15;

  const int srow = (w << 3) + (lane >> 3);
  const int scol = (lane & 7) << 3;
  const int mrow = (w << 4) + (lane >> 2);  // + r*64
  const int mcol = (lane & 3) << 4;

  const _Float16* Qb = Qln + (size_t)bh * 1024 * 64;
  const _Float16* Kb = Kln + (size_t)bh * 1024 * 64;
  const _Float16* Vb = VT + (size_t)bh * 64 * 1024;
  const unsigned char* mb =
      mask + (size_t)b * 1024 * 1024 + (size_t)(qt * 128) * 1024;

  // stage Q (16KB)
#pragma unroll
  for (int r = 0; r < 4; ++r)
    gload16(Qb + (size_t)(qt * 128 + r * 32 + srow) * 64 + scol,
            &Qs[(r * 32 + (w << 3)) * 64]);
  asm volatile("s_waitcnt vmcnt(0)" ::: "memory");
  __syncthreads();

  half8 qf[2][2];
#pragma unroll
  for (int mi = 0; mi < 2; ++mi)
#pragma unroll
    for (int kk = 0; kk < 2; ++kk)
      qf[mi][kk] =
          *(const half8*)&Qs[(w * 32 + mi * 16 + l15) * 64 + kk * 32 + g * 8];

  f32x4 o[2][4];
  float mrun[2][4], lrun[2][4];
#pragma unroll
  for (int mi = 0; mi < 2; ++mi)
#pragma unroll
    for (int dn = 0; dn < 4; ++dn) o[mi][dn] = fzero4();
#pragma unroll
  for (int mi = 0; mi < 2; ++mi)
#pragma unroll
    for (int j = 0; j < 4; ++j) { mrun[mi][j] = -1e30f; lrun[mi][j] = 0.f; }

  for (int kt = 0; kt < 16; ++kt) {
    __syncthreads();
#pragma unroll
    for (int r = 0; r < 2; ++r) {
      gload16(Kb + (size_t)(kt * 64 + r * 32 + srow) * 64 + scol,
              &Ks[(r * 32 + (w << 3)) * 64]);
      gload16(Vb + (size_t)(r * 32 + srow) * 1024 + kt * 64 + scol,
              &Vs[(r * 32 + (w << 3)) * 64]);
      gload16(mb + (size_t)(r * 64 + mrow) * 1024 + kt * 64 + mcol,
              &Ms[(r * 64 + (w << 4)) * 64]);
    }
    asm volatile("s_waitcnt vmcnt(0)" ::: "memory");
    __syncthreads();

    // S = Q K^T
    f32x4 s[2][4];
#pragma unroll
    for (int mi = 0; mi < 2; ++mi)
#pragma unroll
      for (int nj = 0; nj < 4; ++nj) s[mi][nj] = fzero4();
#pragma unroll
    for (int kk = 0; kk < 2; ++kk) {
      half8 kf[4];
#pragma unroll
      for (int nj = 0; nj < 4; ++nj)
        kf[nj] = *(const half8*)&Ks[(nj * 16 + l15) * 64 + kk * 32 + g * 8];
#pragma unroll
      for (int mi = 0; mi < 2; ++mi)
#pragma unroll
        for (int nj = 0; nj < 4; ++nj)
          s[mi][nj] = MFMA(qf[mi][kk], kf[nj], s[mi][nj]);
    }

    // mask + scale + online softmax; stash P (fp16) in LDS
#pragma unroll
    for (int mi = 0; mi < 2; ++mi) {
#pragma unroll
      for (int j = 0; j < 4; ++j) {
        const int lrow = w * 32 + mi * 16 + g * 4 + j;
        float mx = -1e30f;
#pragma unroll
        for (int nj = 0; nj < 4; ++nj) {
          float v = s[mi][nj][j] * 0.125f;
          if (Ms[lrow * 64 + nj * 16 + l15]) v = -1e30f;
          s[mi][nj][j] = v;
          mx = fmaxf(mx, v);
        }
#pragma unroll
        for (int m = 1; m < 16; m <<= 1) mx = fmaxf(mx, __shfl_xor(mx, m, 64));
        const float mnew = fmaxf(mrun[mi][j], mx);
        const float alpha = __expf(mrun[mi][j] - mnew);
        mrun[mi][j] = mnew;
        float rsum = 0.f;
#pragma unroll
        for (int nj = 0; nj < 4; ++nj) {
          float p = __expf(s[mi][nj][j] - mnew);
          s[mi][nj][j] = p;
          rsum += p;
        }
#pragma unroll
        for (int m = 1; m < 16; m <<= 1) rsum += __shfl_xor(rsum, m, 64);
        lrun[mi][j] = lrun[mi][j] * alpha + rsum;
#pragma unroll
        for (int dn = 0; dn < 4; ++dn) o[mi][dn][j] *= alpha;
#pragma unroll
        for (int nj = 0; nj < 4; ++nj)
          Ps[lrow * 72 + nj * 16 + l15] = (_Float16)s[mi][nj][j];
      }
    }

    // O += P V  (A-frags from Ps, B-frags from transposed Vs)
#pragma unroll
    for (int kk = 0; kk < 2; ++kk) {
      half8 pa[2], vbf[4];
#pragma unroll
      for (int mi = 0; mi < 2; ++mi)
        pa[mi] =
            *(const half8*)&Ps[(w * 32 + mi * 16 + l15) * 72 + kk * 32 + g * 8];
#pragma unroll
      for (int dn = 0; dn < 4; ++dn)
        vbf[dn] = *(const half8*)&Vs[(dn * 16 + l15) * 64 + kk * 32 + g * 8];
#pragma unroll
      for (int mi = 0; mi < 2; ++mi)
#pragma unroll
        for (int dn = 0; dn < 4; ++dn)
          o[mi][dn] = MFMA(pa[mi], vbf[dn], o[mi][dn]);
    }
  }

  // normalize + write x as [B,T,H*64] fp16
#pragma unroll
  for (int mi = 0; mi < 2; ++mi) {
#pragma unroll
    for (int j = 0; j < 4; ++j) {
      const int t = qt * 128 + w * 32 + mi * 16 + g * 4 + j;
      const float inv = 1.0f / lrun[mi][j];
      _Float16* xrow = X + ((size_t)(b * 1024 + t)) * 1024 + h * 64;
#pragma unroll
      for (int dn = 0; dn < 4; ++dn)
        xrow[dn * 16 + l15] = (_Float16)(o[mi][dn][j] * inv);
    }
  }
}

// ---------------------------------------------------------------- out proj
__global__ __launch_bounds__(256) void ogemm_kernel(
    const _Float16* __restrict__ Xin, const _Float16* __restrict__ Wo16,
    const float* __restrict__ bo, float* __restrict__ out) {
  __shared__ _Float16 As[128 * 64];
  __shared__ _Float16 Bs[128 * 64];

  const int tid = threadIdx.x;
  const int w = tid >> 6, lane = tid & 63, g = lane >> 4, l15 = lane & 15;
  const int bn = blockIdx.x;  // 0..7
  const int bm = blockIdx.y;  // 0..31
  const int wr = w >> 1, wc = w & 1;
  const int srow = (w << 3) + (lane >> 3);
  const int scol = (lane & 7) << 3;

  f32x4 acc[4][4];
#pragma unroll
  for (int i = 0; i < 4; ++i)
#pragma unroll
    for (int j = 0; j < 4; ++j) acc[i][j] = fzero4();

  for (int kt = 0; kt < 16; ++kt) {
    __syncthreads();
#pragma unroll
    for (int r = 0; r < 4; ++r) {
      const int row = r * 32 + srow;
      gload16(Xin + (size_t)(bm * 128 + row) * 1024 + kt * 64 + scol,
              &As[(r * 32 + (w << 3)) * 64]);
      gload16(Wo16 + (size_t)(bn * 128 + row) * 1024 + kt * 64 + scol,
              &Bs[(r * 32 + (w << 3)) * 64]);
    }
    asm volatile("s_waitcnt vmcnt(0)" ::: "memory");
    __syncthreads();

#pragma unroll
    for (int kk = 0; kk < 2; ++kk) {
      half8 a[4], b[4];
#pragma unroll
      for (int mi = 0; mi < 4; ++mi)
        a[mi] = *(const half8*)&As[(wr * 64 + mi * 16 + l15) * 64 + kk * 32 + g * 8];
#pragma unroll
      for (int nj = 0; nj < 4; ++nj)
        b[nj] = *(const half8*)&Bs[(wc * 64 + nj * 16 + l15) * 64 + kk * 32 + g * 8];
#pragma unroll
      for (int mi = 0; mi < 4; ++mi)
#pragma unroll
        for (int nj = 0; nj < 4; ++nj)
          acc[mi][nj] = MFMA(a[mi], b[nj], acc[mi][nj]);
    }
  }

  const int colbase = bn * 128 + wc * 64;
  const int rowbase = bm * 128 + wr * 64;
  float biasv[4];
#pragma unroll
  for (int nj = 0; nj < 4; ++nj) biasv[nj] = bo[colbase + nj * 16 + l15];
#pragma unroll
  for (int mi = 0; mi < 4; ++mi)
#pragma unroll
    for (int nj = 0; nj < 4; ++nj)
#pragma unroll
      for (int j = 0; j < 4; ++j) {
        const int r = rowbase + mi * 16 + g * 4 + j;
        out[(size_t)r * 1024 + colbase + nj * 16 + l15] =
            acc[mi][nj][j] + biasv[nj];
      }
}

// ---------------------------------------------------------------- launch
extern "C" void kernel_launch(void* const* d_in, const int* in_sizes, int n_in,
                              void* d_out, int out_size, void* d_ws,
                              size_t ws_size, hipStream_t stream) {
  const float* query = (const float*)d_in[0];
  const float* key = (const float*)d_in[1];
  const float* value = (const float*)d_in[2];
  const unsigned char* mask = (const unsigned char*)d_in[3];
  const float* Wq = (const float*)d_in[4];
  const float* bq = (const float*)d_in[5];
  const float* Wk = (const float*)d_in[6];
  const float* bk = (const float*)d_in[7];
  const float* Wv = (const float*)d_in[8];
  const float* bv = (const float*)d_in[9];
  const float* Wo = (const float*)d_in[10];
  const float* bo = (const float*)d_in[11];
  const float* qg = (const float*)d_in[12];
  const float* qb = (const float*)d_in[13];
  const float* kg = (const float*)d_in[14];
  const float* kb = (const float*)d_in[15];
  float* out = (float*)d_out;

  const size_t M4 = (size_t)4 * 1024 * 1024;  // elements
  const size_t M1 = (size_t)1024 * 1024;
  _Float16* q16 = (_Float16*)d_ws;
  _Float16* k16 = q16 + M4;
  _Float16* v16 = k16 + M4;
  _Float16* w16 = v16 + M4;  // Wq,Wk,Wv,Wo concat (4M elems)
  _Float16* Qln = w16 + M4;
  _Float16* Kln = Qln + M4;
  _Float16* VTp = Kln + M4;
  _Float16* X = VTp + M4;  // total 64 MB
  // mask8 reuses the q16 region (dead after proj_kernel)
  unsigned char* mask8 = (unsigned char*)q16;

  CvtArgs ca;
  ca.src[0] = query; ca.src[1] = key; ca.src[2] = value;
  ca.src[3] = Wq; ca.src[4] = Wk; ca.src[5] = Wv; ca.src[6] = Wo;
  ca.dst[0] = q16; ca.dst[1] = k16; ca.dst[2] = v16;
  ca.dst[3] = w16; ca.dst[4] = w16 + M1; ca.dst[5] = w16 + 2 * M1;
  ca.dst[6] = w16 + 3 * M1;
  ca.n[0] = ca.n[1] = ca.n[2] = (int)M4;
  ca.n[3] = ca.n[4] = ca.n[5] = ca.n[6] = (int)M1;

  cvt_kernel<<<dim3(512, 7), 256, 0, stream>>>(ca);
  proj_kernel<<<dim3(8, 32, 3), 256, 0, stream>>>(
      q16, k16, v16, w16, bq, bk, bv, qg, qb, kg, kb, Qln, Kln, VTp);
  maskcvt_kernel<<<dim3(1024), 256, 0, stream>>>(mask, mask8, (int)M4);
  attn_kernel<<<dim3(8, 64), 256, 0, stream>>>(Qln, Kln, VTp, mask8, X);
  ogemm_kernel<<<dim3(8, 32), 256, 0, stream>>>(X, w16 + 3 * M1, bo, out);
}